// Round 9
// baseline (594.683 us; speedup 1.0000x reference)
//
#include <hip/hip_runtime.h>
#include <hip/hip_bf16.h>
#include <stdint.h>

typedef __bf16 bf16_t;
typedef __bf16 bf16x8 __attribute__((ext_vector_type(8)));
typedef float f32x4 __attribute__((ext_vector_type(4)));

#define LOG2E 1.44269504088896340736f
#define LN2 0.69314718055994530942f

__device__ __forceinline__ float fast_exp2(float x) { return __builtin_amdgcn_exp2f(x); }
__device__ __forceinline__ float fast_log2(float x) { return __builtin_amdgcn_logf(x); }
__device__ __forceinline__ float fast_rcp(float x) { return __builtin_amdgcn_rcpf(x); }

// arg pre-scaled by LOG2E: softplus(x), t = x*LOG2E
__device__ __forceinline__ float softplus_t(float t) {
    float sp = LN2 * fast_log2(1.0f + fast_exp2(t));
    return (t > 28.9f) ? t * LN2 : sp;
}
// arg pre-scaled by 2*LOG2E: tanh(x), t = 2x*LOG2E
__device__ __forceinline__ float tanh_t(float t) {
    float e = fast_exp2(t);
    return 1.0f - 2.0f * fast_rcp(1.0f + e);
}

// packed f32x2 -> bf16x2 (RNE): lo16 = cvt(a), hi16 = cvt(b)
__device__ __forceinline__ uint32_t cvt_pk(float a, float b) {
    uint32_t r;
    asm("v_cvt_pk_bf16_f32 %0, %1, %2" : "=v"(r) : "v"(a), "v"(b));
    return r;
}

// lane l <-> l^16 exchange (validated r7/r8)
__device__ __forceinline__ float swz16(float v) {
    int r = __builtin_amdgcn_ds_swizzle(__builtin_bit_cast(int, v), 0x401F);
    return __builtin_bit_cast(float, r);
}

// B=4096, L=64, C=7, H=32, K=2 -> 504 RK4 stages, h=0.5
// Grid 512 x 8 batch rows; block = 256 threads (4 waves); 2 blocks/CU so each
// SIMD hosts 2 waves from INDEPENDENT barrier domains (anti-phase stall hiding).
// Phase A (GEMV1^T): D1[i][b]=W1p@z^T, wave w -> tile w&1, reg pair w>>1.
// Phase B (GEMV2^T): D2[n][b]=W2p@h1^T, wave w -> tiles 4w..4w+3; in-lane
// c-contraction + swz16; 2 duty z per lane. Batch cols 8..15 zero-fed.
__global__ __launch_bounds__(256, 2) void cde_kernel(
    const float* __restrict__ x,    // (4096,64,7)
    const float* __restrict__ Wi,   // (32,7)
    const float* __restrict__ bi,   // (32,)
    const float* __restrict__ W1,   // (32,32)
    const float* __restrict__ b1,   // (32,)
    const float* __restrict__ W2,   // (224,32)
    const float* __restrict__ b2,   // (224,)
    const float* __restrict__ Wo1,  // (16,32)
    const float* __restrict__ bo1,  // (16,)
    const float* __restrict__ Wo2,  // (3,16)
    const float* __restrict__ bo2,  // (3,)
    float* __restrict__ out)        // (4096,3)
{
    __shared__ float diffs[8][441];                     // [b][i*7+c]
    __shared__ alignas(16) float dxA[16][12];           // [b][c], cols>=7 and rows>=8 zero
    __shared__ alignas(16) float dxB[16][12];
    __shared__ alignas(16) uint16_t zhS[4][16][8], zlS[4][16][8];  // [kchunk][b][kpos]
    __shared__ alignas(16) uint16_t hhS[4][16][8], hlS[4][16][8];  // [ichunk][b][ipos]
    __shared__ float zfin[16][32];
    __shared__ float wo1t[32][16];
    __shared__ float ubuf[8][16];

    const int tid = threadIdx.x;
    const int l = tid & 63;
    const int w = tid >> 6;          // wave 0..3
    const int r0 = blockIdx.x * 8;

    const int ar = l & 15;           // A-row / B-col(batch) / D-col(batch)
    const int q = l >> 4;            // k-chunk / D-row quarter
    const int qlo = q & 1, qhi = q >> 1;
    const bool brow = ar < 8;

    // phase-A duty: tile T1, D-regs {2rp, 2rp+1} -> i1a, i1a+1
    const int T1 = w & 1, rp = w >> 1;

    // phase-B duty: z[b=ar][h2a], z[b=ar][h2b]
    const int h2a = 8 * w + 4 * qlo + qhi;
    const int h2b = h2a + 2;

    // dx producer duty: wave w -> batch rows {2w, 2w+1}
    const int bdx = 2 * w + (l >> 5);
    const int cdx = l & 31;
    const bool dxact = cdx < 7;

    // ---- W1 A-frag (tile T1) + bias, pre-scaled LOG2E, hi/lo split ----
    bf16x8 a1h, a1l;
    {
        const float* p = &W1[(16 * T1 + ar) * 32 + 8 * q];
#pragma unroll
        for (int j = 0; j < 8; ++j) {
            float v = p[j] * LOG2E;
            bf16_t hh = (bf16_t)v;
            a1h[j] = hh;
            a1l[j] = (bf16_t)(v - (float)hh);
        }
    }
    f32x4 b1v;
#pragma unroll
    for (int r = 0; r < 4; ++r) b1v[r] = b1[16 * T1 + 4 * q + r] * LOG2E;

    // ---- W2 A-frags (tiles 4w..4w+3) + bias, pre-scaled 2*LOG2E ----
    bf16x8 a2h[4], a2l[4];
    f32x4 b2v[4];
#pragma unroll
    for (int t = 0; t < 4; ++t) {
        const int T = 4 * w + t;
        const int hrow = 2 * T + (ar >> 3);
        const int cc = ar & 7;
        if (cc < 7) {
            const float* p = &W2[(hrow * 7 + cc) * 32 + 8 * q];
#pragma unroll
            for (int j = 0; j < 8; ++j) {
                float v = p[j] * (2.0f * LOG2E);
                bf16_t hv = (bf16_t)v;
                a2h[t][j] = hv;
                a2l[t][j] = (bf16_t)(v - (float)hv);
            }
        } else {
#pragma unroll
            for (int j = 0; j < 8; ++j) { a2h[t][j] = (bf16_t)0.0f; a2l[t][j] = (bf16_t)0.0f; }
        }
#pragma unroll
        for (int r = 0; r < 4; ++r) {
            int c = 4 * qlo + r;
            int hq = 2 * T + qhi;
            b2v[t][r] = (c < 7) ? b2[hq * 7 + c] * (2.0f * LOG2E) : 0.0f;
        }
    }

    // ---- hoisted LDS pointers (reads are addr = 16*lane: conflict-free) ----
    const bf16x8* pZh = (const bf16x8*)&zhS[q][ar][0];
    const bf16x8* pZl = (const bf16x8*)&zlS[q][ar][0];
    const bf16x8* pHh = (const bf16x8*)&hhS[q][ar][0];
    const bf16x8* pHl = (const bf16x8*)&hlS[q][ar][0];
    const f32x4* pDxA = (const f32x4*)&dxA[ar][4 * qlo];
    const f32x4* pDxB = (const f32x4*)&dxB[ar][4 * qlo];
    uint32_t* pWh = (uint32_t*)&hhS[2 * T1 + qhi][ar][4 * qlo + 2 * rp];  // b32 pair
    uint32_t* pWl = (uint32_t*)&hlS[2 * T1 + qhi][ar][4 * qlo + 2 * rp];
    uint16_t* pZ0h = &zhS[w][ar][4 * qlo + qhi];
    uint16_t* pZ0l = &zlS[w][ar][4 * qlo + qhi];
    uint16_t* pZ1h = &zhS[w][ar][4 * qlo + qhi + 2];
    uint16_t* pZ1l = &zlS[w][ar][4 * qlo + qhi + 2];

    // ---- prologue: zero feeds, stage diffs + wo1t ----
    ((uint32_t*)zhS)[tid] = 0;
    ((uint32_t*)zlS)[tid] = 0;
    ((uint32_t*)hhS)[tid] = 0;
    ((uint32_t*)hlS)[tid] = 0;
    if (tid < 192) { ((float*)dxA)[tid] = 0.0f; ((float*)dxB)[tid] = 0.0f; }
    for (int e = tid; e < 8 * 441; e += 256) {
        int r = e / 441, rem = e - r * 441;
        const float* px = &x[(size_t)(r0 + r) * 448];
        diffs[r][rem] = px[rem + 7] - px[rem];
    }
    for (int e = tid; e < 512; e += 256)
        wo1t[e >> 4][e & 15] = Wo1[(e & 15) * 32 + (e >> 4)];
    __syncthreads();

    // ---- z0 at duties (rows >=8 stay exactly 0) + dx(t=0) ----
    float zb0 = 0.0f, zb1 = 0.0f, ka0 = 0.0f, ka1 = 0.0f;
    if (brow) {
        const float* px = &x[(size_t)(r0 + ar) * 448];
        float a0 = bi[h2a], a1 = bi[h2b];
#pragma unroll
        for (int c = 0; c < 7; ++c) {
            a0 += px[c] * Wi[h2a * 7 + c];
            a1 += px[c] * Wi[h2b * 7 + c];
        }
        zb0 = a0; zb1 = a1;
    }
    {
        uint32_t rh = cvt_pk(zb0, zb1);
        float f0 = __builtin_bit_cast(float, rh << 16);
        float f1 = __builtin_bit_cast(float, rh & 0xffff0000u);
        uint32_t rl = cvt_pk(zb0 - f0, zb1 - f1);
        *pZ0h = (uint16_t)rh; *pZ1h = (uint16_t)(rh >> 16);
        *pZ0l = (uint16_t)rl; *pZ1l = (uint16_t)(rl >> 16);
    }
    if (dxact) dxA[bdx][cdx] = diffs[bdx][cdx];
    __syncthreads();

    const f32x4 zero4 = {0.0f, 0.0f, 0.0f, 0.0f};

    for (int k = 0; k < 126; ++k) {
#pragma unroll
        for (int s = 0; s < 4; ++s) {
            // ---------- phase A: GEMV1^T + dx producer ----------
            {
                bf16x8 bzh = *pZh;
                bf16x8 bzl = *pZl;
                f32x4 m1 = __builtin_amdgcn_mfma_f32_16x16x32_bf16(a1h, bzh, b1v, 0, 0, 0);
                f32x4 m2 = __builtin_amdgcn_mfma_f32_16x16x32_bf16(a1h, bzl, zero4, 0, 0, 0);
                f32x4 m3 = __builtin_amdgcn_mfma_f32_16x16x32_bf16(a1l, bzh, zero4, 0, 0, 0);
                f32x4 S = m1 + m2 + m3;
                float Xa = rp ? S[2] : S[0];
                float Xb = rp ? S[3] : S[1];
                float spa = softplus_t(Xa);
                float spb = softplus_t(Xb);
                uint32_t rh = cvt_pk(spa, spb);
                float f0 = __builtin_bit_cast(float, rh << 16);
                float f1 = __builtin_bit_cast(float, rh & 0xffff0000u);
                uint32_t rl = cvt_pk(spa - f0, spb - f1);
                *pWh = rh;
                *pWl = rl;
            }
            if ((s == 0 || s == 1) && dxact) {   // one stage ahead
                int m = 2 * k + 1 + s;           // s=0 -> dxB(m=2k+1), s=1 -> dxA(m=2k+2)
                int i = m >> 2; if (i > 62) i = 62;
                float f = 0.25f * (float)(m - 4 * i);
                float D = diffs[bdx][i * 7 + cdx];
                float a = diffs[bdx][(i > 0 ? i - 1 : 0) * 7 + cdx];
                float val = a + (D - a) * (f * (4.0f - 3.0f * f));
                if (s == 0) dxB[bdx][cdx] = val;
                else        dxA[bdx][cdx] = val;
            }
            __syncthreads();

            // ---------- phase B: GEMV2^T + in-lane contraction + RK4 ----------
            {
                bf16x8 bhh = *pHh;
                bf16x8 bhl = *pHl;
                f32x4 dxv = (s == 0 || s == 3) ? *pDxA : *pDxB;
                float ks0, ks1, ks2, ks3;
#pragma unroll
                for (int t = 0; t < 4; ++t) {
                    f32x4 n1 = __builtin_amdgcn_mfma_f32_16x16x32_bf16(a2h[t], bhh, b2v[t], 0, 0, 0);
                    f32x4 n2 = __builtin_amdgcn_mfma_f32_16x16x32_bf16(a2h[t], bhl, zero4, 0, 0, 0);
                    f32x4 n3 = __builtin_amdgcn_mfma_f32_16x16x32_bf16(a2l[t], bhh, zero4, 0, 0, 0);
                    f32x4 S2 = n1 + n2 + n3;
                    float pk = tanh_t(S2[0]) * dxv[0] + tanh_t(S2[1]) * dxv[1]
                             + tanh_t(S2[2]) * dxv[2] + tanh_t(S2[3]) * dxv[3];
                    float kst = pk + swz16(pk);
                    if (t == 0) ks0 = kst; else if (t == 1) ks1 = kst;
                    else if (t == 2) ks2 = kst; else ks3 = kst;
                }
                float kd0 = qlo ? ks2 : ks0;
                float kd1 = qlo ? ks3 : ks1;
                float zs0, zs1;
                if (s == 0) {
                    ka0 = kd0; ka1 = kd1;
                    zs0 = zb0 + 0.25f * kd0; zs1 = zb1 + 0.25f * kd1;
                } else if (s == 1) {
                    ka0 += 2.0f * kd0; ka1 += 2.0f * kd1;
                    zs0 = zb0 + 0.25f * kd0; zs1 = zb1 + 0.25f * kd1;
                } else if (s == 2) {
                    ka0 += 2.0f * kd0; ka1 += 2.0f * kd1;
                    zs0 = zb0 + 0.5f * kd0; zs1 = zb1 + 0.5f * kd1;
                } else {
                    zb0 += (1.0f / 12.0f) * (ka0 + kd0);
                    zb1 += (1.0f / 12.0f) * (ka1 + kd1);
                    zs0 = zb0; zs1 = zb1;
                }
                uint32_t rh = cvt_pk(zs0, zs1);
                float f0 = __builtin_bit_cast(float, rh << 16);
                float f1 = __builtin_bit_cast(float, rh & 0xffff0000u);
                uint32_t rl = cvt_pk(zs0 - f0, zs1 - f1);
                *pZ0h = (uint16_t)rh; *pZ1h = (uint16_t)(rh >> 16);
                *pZ0l = (uint16_t)rl; *pZ1l = (uint16_t)(rl >> 16);
            }
            __syncthreads();
        }
    }

    // ---- epilogue: out = softplus(z @ Wo1^T + bo1) @ Wo2^T + bo2 ----
    zfin[ar][h2a] = zb0;
    zfin[ar][h2b] = zb1;
    __syncthreads();
    if (tid < 128) {
        int r = tid >> 4, jj = tid & 15;
        float acc = bo1[jj];
#pragma unroll
        for (int hh = 0; hh < 32; ++hh) acc += zfin[r][hh] * wo1t[hh][jj];
        ubuf[r][jj] = softplus_t(acc * LOG2E);
    }
    __syncthreads();
    if (tid < 24) {
        int r = tid / 3, o = tid - 3 * (tid / 3);
        float acc = bo2[o];
#pragma unroll
        for (int j = 0; j < 16; ++j) acc += ubuf[r][j] * Wo2[o * 16 + j];
        out[(size_t)(r0 + r) * 3 + o] = acc;
    }
}

extern "C" void kernel_launch(void* const* d_in, const int* in_sizes, int n_in,
                              void* d_out, int out_size, void* d_ws, size_t ws_size,
                              hipStream_t stream) {
    (void)in_sizes; (void)n_in; (void)d_ws; (void)ws_size; (void)out_size;
    const float* x   = (const float*)d_in[0];
    const float* Wi  = (const float*)d_in[1];
    const float* bi  = (const float*)d_in[2];
    const float* W1  = (const float*)d_in[3];
    const float* b1  = (const float*)d_in[4];
    const float* W2  = (const float*)d_in[5];
    const float* b2  = (const float*)d_in[6];
    const float* Wo1 = (const float*)d_in[7];
    const float* bo1 = (const float*)d_in[8];
    const float* Wo2 = (const float*)d_in[9];
    const float* bo2 = (const float*)d_in[10];
    cde_kernel<<<dim3(512), dim3(256), 0, stream>>>(x, Wi, bi, W1, b1, W2, b2,
                                                    Wo1, bo1, Wo2, bo2, (float*)d_out);
}